// Round 18
// baseline (94.367 us; speedup 1.0000x reference)
//
#include <hip/hip_runtime.h>
#include <hip/hip_fp16.h>
#include <math.h>

// GraphAttention: Q=4, N=50000, K=8, F_IN=128, F_OUT=64
//   y  = query @ W1        (single-pass f16 MFMA; f16 out)
//   s1 = tanh(mean_k y[e]+b1) . W2
//   score = mean_k s1[e] + b2
//   softmax without max-sub (scores bounded ~|2|): w=exp(s)/Z
//   ctx = (sum_n exp(s_n) * values[n]) / Z
// This round: k_xw shares one W1 pack across 2 q's per block;
// k_agg 8 chains/wave (64 gathers in flight, launch_bounds(256,3)).

#define FIN 128
#define FOUT 64
#define KN 8
#define CTXB 250            // chunks per q
#define CHUNK 200           // nodes per chunk

typedef _Float16 f16x8 __attribute__((ext_vector_type(8)));
typedef float f32x4 __attribute__((ext_vector_type(4)));

// ---------------- Stage 1: y = query @ W1 (f16 MFMA), 2 q's per block ----------------
__global__ __launch_bounds__(256, 3) void k_xw(const float* __restrict__ query,
                                               const float* __restrict__ W1,
                                               __half* __restrict__ y, int N) {
    __shared__ _Float16 Wlds[8192];   // [16 frags][64 lanes][8 f16]
    const int tid = threadIdx.x;
    const int wave = tid >> 6, lane = tid & 63;
    const int lg = lane >> 4, lr = lane & 15;
    const int q0 = blockIdx.y * 2;
    const int base = blockIdx.x * 128 + wave * 32;

    int n0 = base + lr;       if (n0 >= N) n0 = N - 1;
    int n1 = base + 16 + lr;  if (n1 >= N) n1 = N - 1;

    // ---- issue q0's query loads first (in flight during the pack) ----
    const float* qb0 = query + (size_t)q0 * N * FIN;
    const float4* r0 = (const float4*)(qb0 + (size_t)n0 * FIN);
    const float4* r1 = (const float4*)(qb0 + (size_t)n1 * FIN);
    float4 a0[8], a1[8];
    #pragma unroll
    for (int kk = 0; kk < 4; ++kk) {
        a0[2 * kk]     = r0[kk * 8 + lg * 2];
        a0[2 * kk + 1] = r0[kk * 8 + lg * 2 + 1];
        a1[2 * kk]     = r1[kk * 8 + lg * 2];
        a1[2 * kk + 1] = r1[kk * 8 + lg * 2 + 1];
    }

    // ---- pack W1 -> LDS (overlaps pending query loads) ----
    #pragma unroll
    for (int it = 0; it < 4; ++it) {
        int p = it * 256 + tid;        // fragment-row 0..1023
        int g6 = p >> 6;               // kk*4+nt
        int kk = g6 >> 2, nt = g6 & 3;
        int lane6 = p & 63;
        int plg = lane6 >> 4, plr = lane6 & 15;
        int f = nt * 16 + plr;
        int kbase = kk * 32 + plg * 8;
        f16x8 fr;
        #pragma unroll
        for (int j = 0; j < 8; ++j)
            fr[j] = (_Float16)W1[(kbase + j) * FOUT + f];
        ((f16x8*)Wlds)[p] = fr;
    }
    __syncthreads();
    const f16x8* Bp = (const f16x8*)Wlds;

    for (int qi = 0; qi < 2; ++qi) {
        const int q = q0 + qi;
        __half* yq = y + (size_t)q * N * FOUT;
        if (qi == 1) {     // load q1's rows (pack already resident)
            const float* qb = query + (size_t)q * N * FIN;
            const float4* s0 = (const float4*)(qb + (size_t)n0 * FIN);
            const float4* s1p = (const float4*)(qb + (size_t)n1 * FIN);
            #pragma unroll
            for (int kk = 0; kk < 4; ++kk) {
                a0[2 * kk]     = s0[kk * 8 + lg * 2];
                a0[2 * kk + 1] = s0[kk * 8 + lg * 2 + 1];
                a1[2 * kk]     = s1p[kk * 8 + lg * 2];
                a1[2 * kk + 1] = s1p[kk * 8 + lg * 2 + 1];
            }
        }

        f32x4 acc0[4], acc1[4];
        #pragma unroll
        for (int nt = 0; nt < 4; ++nt) { acc0[nt] = (f32x4)0.f; acc1[nt] = (f32x4)0.f; }

        #pragma unroll
        for (int kk = 0; kk < 4; ++kk) {
            f16x8 A0, A1;
            const float* x0 = (const float*)&a0[2 * kk];
            const float* x1 = (const float*)&a1[2 * kk];
            #pragma unroll
            for (int j = 0; j < 8; ++j) { A0[j] = (_Float16)x0[j]; A1[j] = (_Float16)x1[j]; }
            #pragma unroll
            for (int nt = 0; nt < 4; ++nt) {
                f16x8 Bf = Bp[(kk * 4 + nt) * 64 + lane];
                acc0[nt] = __builtin_amdgcn_mfma_f32_16x16x32_f16(A0, Bf, acc0[nt], 0, 0, 0);
                acc1[nt] = __builtin_amdgcn_mfma_f32_16x16x32_f16(A1, Bf, acc1[nt], 0, 0, 0);
            }
        }
        #pragma unroll
        for (int r = 0; r < 4; ++r) {
            int m0 = base + lg * 4 + r;
            int m1 = base + 16 + lg * 4 + r;
            if (m0 < N) {
                #pragma unroll
                for (int nt = 0; nt < 4; ++nt)
                    yq[(size_t)m0 * FOUT + nt * 16 + lr] = __float2half(acc0[nt][r]);
            }
            if (m1 < N) {
                #pragma unroll
                for (int nt = 0; nt < 4; ++nt)
                    yq[(size_t)m1 * FOUT + nt * 16 + lr] = __float2half(acc1[nt][r]);
            }
        }
    }
}

// ---------------- Stage 2: s1 = tanh(mean_k y[e]+b1).W2 ----------------
// 8 node-chains per wave-half: 64 independent gathers in flight.
__global__ __launch_bounds__(256, 3) void k_agg(const __half* __restrict__ y,
                                                const int* __restrict__ edges,
                                                const float* __restrict__ b1,
                                                const float* __restrict__ W2,
                                                float* __restrict__ s1, int N) {
    const int tid = threadIdx.x;
    const int wave = tid >> 6, lane = tid & 63;
    const int half = lane >> 5, fl = lane & 31;
    const int q = blockIdx.y;
    const int base = blockIdx.x * 64 + wave * 16 + half;   // chains at base+2c
    const __half2* y2 = (const __half2*)(y + (size_t)q * N * FOUT);

    int n[8], nc[8];
    #pragma unroll
    for (int c = 0; c < 8; ++c) {
        n[c] = base + 2 * c;
        nc[c] = n[c] < N ? n[c] : N - 1;
    }
    int4 ea[8], eb[8];
    #pragma unroll
    for (int c = 0; c < 8; ++c) {
        const int4* er = (const int4*)(edges + (size_t)nc[c] * KN);
        ea[c] = er[0];
        eb[c] = er[1];
    }
    __half2 v[8][8];
    #pragma unroll
    for (int c = 0; c < 8; ++c) {
        v[c][0] = y2[(size_t)ea[c].x * 32 + fl];
        v[c][1] = y2[(size_t)ea[c].y * 32 + fl];
        v[c][2] = y2[(size_t)ea[c].z * 32 + fl];
        v[c][3] = y2[(size_t)ea[c].w * 32 + fl];
        v[c][4] = y2[(size_t)eb[c].x * 32 + fl];
        v[c][5] = y2[(size_t)eb[c].y * 32 + fl];
        v[c][6] = y2[(size_t)eb[c].z * 32 + fl];
        v[c][7] = y2[(size_t)eb[c].w * 32 + fl];
    }

    float2 bv = *(const float2*)(b1 + fl * 2);
    float2 wv = *(const float2*)(W2 + fl * 2);

    float p[8];
    #pragma unroll
    for (int c = 0; c < 8; ++c) {
        __half2 s01 = __hadd2(v[c][0], v[c][1]), s23 = __hadd2(v[c][2], v[c][3]);
        __half2 s45 = __hadd2(v[c][4], v[c][5]), s67 = __hadd2(v[c][6], v[c][7]);
        __half2 sum = __hadd2(__hadd2(s01, s23), __hadd2(s45, s67));
        float2 sf = __half22float2(sum);
        float x0 = sf.x * 0.125f + bv.x;
        float x1 = sf.y * 0.125f + bv.y;
        float e0 = __expf(-2.f * fabsf(x0)), e1 = __expf(-2.f * fabsf(x1));
        float t0 = copysignf(__fdividef(1.f - e0, 1.f + e0), x0);
        float t1 = copysignf(__fdividef(1.f - e1, 1.f + e1), x1);
        p[c] = t0 * wv.x + t1 * wv.y;
    }
    #pragma unroll
    for (int off = 16; off; off >>= 1) {
        #pragma unroll
        for (int c = 0; c < 8; ++c) p[c] += __shfl_xor(p[c], off);
    }
    if (fl == 0) {
        float* s1q = s1 + (size_t)q * N;
        #pragma unroll
        for (int c = 0; c < 8; ++c)
            if (n[c] < N) s1q[n[c]] = p[c];
    }
}

// ---------------- Stage 3 (fused): score + exp + Z-partial + weighted values ----------------
__global__ __launch_bounds__(256, 4) void k_ctx(const float* __restrict__ values,
                                                const float* __restrict__ s1,
                                                const int* __restrict__ edges,
                                                const float* __restrict__ b2,
                                                float* __restrict__ score,
                                                float* __restrict__ partial,
                                                float* __restrict__ zpart, int N) {
    const int q = blockIdx.y, cb = blockIdx.x;
    const int tid = threadIdx.x;
    const int n0 = cb * CHUNK, n1 = min(n0 + CHUNK, N);
    const int cnt = n1 - n0;
    __shared__ float wlds[256];
    __shared__ float zred[4];
    const float* s1q = s1 + (size_t)q * N;
    const float b2v = b2[0];

    float zp = 0.f;
    if (tid < cnt) {
        int n = n0 + tid;
        float acc = 0.f;
        #pragma unroll
        for (int k = 0; k < KN; ++k) acc += s1q[edges[(size_t)n * KN + k]];
        float sc = acc * 0.125f + b2v;
        score[(size_t)q * N + n] = sc;
        float ex = __expf(sc);
        wlds[tid] = ex;
        zp = ex;
    }
    float z = zp;
    #pragma unroll
    for (int off = 32; off; off >>= 1) z += __shfl_xor(z, off);
    if ((tid & 63) == 0) zred[tid >> 6] = z;
    __syncthreads();

    const int fi = tid & 31, g = tid >> 5;
    const float4* v = (const float4*)(values + (size_t)q * N * FIN);
    float4 acc = make_float4(0.f, 0.f, 0.f, 0.f);
    int n = n0 + g;
    for (; n + 56 < n1; n += 64) {
        int l = n - n0;
        float w0 = wlds[l],      w1 = wlds[l + 8],  w2 = wlds[l + 16], w3 = wlds[l + 24];
        float w4 = wlds[l + 32], w5 = wlds[l + 40], w6 = wlds[l + 48], w7 = wlds[l + 56];
        float4 v0 = v[(size_t)n * 32 + fi];
        float4 v1 = v[(size_t)(n + 8) * 32 + fi];
        float4 v2 = v[(size_t)(n + 16) * 32 + fi];
        float4 v3 = v[(size_t)(n + 24) * 32 + fi];
        float4 v4 = v[(size_t)(n + 32) * 32 + fi];
        float4 v5 = v[(size_t)(n + 40) * 32 + fi];
        float4 v6 = v[(size_t)(n + 48) * 32 + fi];
        float4 v7 = v[(size_t)(n + 56) * 32 + fi];
        acc.x = fmaf(w0, v0.x, acc.x); acc.y = fmaf(w0, v0.y, acc.y);
        acc.z = fmaf(w0, v0.z, acc.z); acc.w = fmaf(w0, v0.w, acc.w);
        acc.x = fmaf(w1, v1.x, acc.x); acc.y = fmaf(w1, v1.y, acc.y);
        acc.z = fmaf(w1, v1.z, acc.z); acc.w = fmaf(w1, v1.w, acc.w);
        acc.x = fmaf(w2, v2.x, acc.x); acc.y = fmaf(w2, v2.y, acc.y);
        acc.z = fmaf(w2, v2.z, acc.z); acc.w = fmaf(w2, v2.w, acc.w);
        acc.x = fmaf(w3, v3.x, acc.x); acc.y = fmaf(w3, v3.y, acc.y);
        acc.z = fmaf(w3, v3.z, acc.z); acc.w = fmaf(w3, v3.w, acc.w);
        acc.x = fmaf(w4, v4.x, acc.x); acc.y = fmaf(w4, v4.y, acc.y);
        acc.z = fmaf(w4, v4.z, acc.z); acc.w = fmaf(w4, v4.w, acc.w);
        acc.x = fmaf(w5, v5.x, acc.x); acc.y = fmaf(w5, v5.y, acc.y);
        acc.z = fmaf(w5, v5.z, acc.z); acc.w = fmaf(w5, v5.w, acc.w);
        acc.x = fmaf(w6, v6.x, acc.x); acc.y = fmaf(w6, v6.y, acc.y);
        acc.z = fmaf(w6, v6.z, acc.z); acc.w = fmaf(w6, v6.w, acc.w);
        acc.x = fmaf(w7, v7.x, acc.x); acc.y = fmaf(w7, v7.y, acc.y);
        acc.z = fmaf(w7, v7.z, acc.z); acc.w = fmaf(w7, v7.w, acc.w);
    }
    for (; n < n1; n += 8) {
        float ww = wlds[n - n0];
        float4 a = v[(size_t)n * 32 + fi];
        acc.x = fmaf(ww, a.x, acc.x);
        acc.y = fmaf(ww, a.y, acc.y);
        acc.z = fmaf(ww, a.z, acc.z);
        acc.w = fmaf(ww, a.w, acc.w);
    }
    __shared__ float4 part[256];
    part[tid] = acc;
    __syncthreads();
    if (tid < 32) {
        float4 a = part[tid];
        #pragma unroll
        for (int gg = 1; gg < 8; ++gg) {
            float4 b = part[gg * 32 + tid];
            a.x += b.x; a.y += b.y; a.z += b.z; a.w += b.w;
        }
        ((float4*)partial)[((size_t)q * CTXB + cb) * 32 + fi] = a;
    }
    if (tid == 0) zpart[(size_t)q * CTXB + cb] = zred[0] + zred[1] + zred[2] + zred[3];
}

// ---------------- Stage 4: ctx[q,f] = (Σ_cb partial[q,cb,f]) / (Σ_cb zpart[q,cb]) ----------------
__global__ __launch_bounds__(512) void k_final(const float* __restrict__ partial,
                                               const float* __restrict__ zpart,
                                               float* __restrict__ ctx) {
    const int q = blockIdx.x;
    const int tid = threadIdx.x;
    const int f = tid & 127, h = tid >> 7;
    const float* p = partial + (size_t)q * CTXB * FIN;
    float s = 0.f;
    for (int b = h; b < CTXB; b += 4) s += p[(size_t)b * FIN + f];
    __shared__ float red[512];
    __shared__ float zred[8];
    red[tid] = s;
    float z = (tid < CTXB) ? zpart[(size_t)q * CTXB + tid] : 0.f;
    #pragma unroll
    for (int off = 32; off; off >>= 1) z += __shfl_xor(z, off);
    if ((tid & 63) == 0) zred[tid >> 6] = z;
    __syncthreads();
    if (tid < 128) {
        float Zt = zred[0] + zred[1] + zred[2] + zred[3] +
                   zred[4] + zred[5] + zred[6] + zred[7];
        float t = red[tid] + red[tid + 128] + red[tid + 256] + red[tid + 384];
        ctx[q * FIN + f] = t * (1.f / Zt);
    }
}

extern "C" void kernel_launch(void* const* d_in, const int* in_sizes, int n_in,
                              void* d_out, int out_size, void* d_ws, size_t ws_size,
                              hipStream_t stream) {
    const float* query  = (const float*)d_in[0];
    const float* values = (const float*)d_in[1];
    const int*   edges  = (const int*)d_in[2];
    const float* W1     = (const float*)d_in[3];
    const float* b1     = (const float*)d_in[4];
    const float* W2     = (const float*)d_in[5];
    const float* b2     = (const float*)d_in[6];

    int N = in_sizes[2] / KN;                 // 50000
    int Q = in_sizes[0] / (N * FIN);          // 4

    float* out   = (float*)d_out;
    float* ctx   = out;                       // [Q,128]
    float* score = out + (size_t)Q * FIN;     // [Q,N]

    char* ws = (char*)d_ws;
    __half* y = (__half*)ws;                                    // [Q,N,64] f16
    size_t off = (size_t)Q * N * FOUT * sizeof(__half);
    float* s1    = (float*)(ws + off);  off += (size_t)Q * N * sizeof(float);
    float* part  = (float*)(ws + off);  off += (size_t)Q * CTXB * FIN * sizeof(float);
    float* zpart = (float*)(ws + off);                          // [Q,CTXB]

    dim3 g1((N + 127) / 128, Q / 2);
    k_xw<<<g1, 256, 0, stream>>>(query, W1, y, N);
    dim3 g2((N + 63) / 64, Q);
    k_agg<<<g2, 256, 0, stream>>>(y, edges, b1, W2, s1, N);
    dim3 g3(CTXB, Q);
    k_ctx<<<g3, 256, 0, stream>>>(values, s1, edges, b2, score, part, zpart, N);
    k_final<<<Q, 512, 0, stream>>>(part, zpart, ctx);
}

// Round 19
// 85.434 us; speedup vs baseline: 1.1046x; 1.1046x over previous
//
#include <hip/hip_runtime.h>
#include <hip/hip_fp16.h>
#include <math.h>

// GraphAttention: Q=4, N=50000, K=8, F_IN=128, F_OUT=64
//   y  = query @ W1        (single-pass f16 MFMA; f16 out)
//   s1 = tanh(mean_k y[e]+b1) . W2
//   score = mean_k s1[e] + b2
//   softmax without max-sub (scores bounded ~|2|): w=exp(s)/Z
//   ctx = (sum_n exp(s_n) * values[n]) / Z
// FINAL (R16 config, best measured 85.4us): 4 launches; k_xw with
// query-loads-before-pack; k_agg 4 chains/wave; fused k_ctx; k_final.
// Documented dead ends: coop mega-kernel (occupancy collapse), per-block
// threadfence reduce (cross-XCD serialization), 8-chain k_agg (spills).

#define FIN 128
#define FOUT 64
#define KN 8
#define CTXB 250            // chunks per q
#define CHUNK 200           // nodes per chunk

typedef _Float16 f16x8 __attribute__((ext_vector_type(8)));
typedef float f32x4 __attribute__((ext_vector_type(4)));

// ---------------- Stage 1: y = query @ W1 (f16 MFMA) ----------------
__global__ __launch_bounds__(256, 3) void k_xw(const float* __restrict__ query,
                                               const float* __restrict__ W1,
                                               __half* __restrict__ y, int N) {
    __shared__ _Float16 Wlds[8192];   // [16 frags][64 lanes][8 f16]
    const int tid = threadIdx.x;
    const int wave = tid >> 6, lane = tid & 63;
    const int lg = lane >> 4, lr = lane & 15;
    const int q = blockIdx.y;
    const int base = blockIdx.x * 128 + wave * 32;
    const float* qb = query + (size_t)q * N * FIN;
    __half* yq = y + (size_t)q * N * FOUT;

    // ---- issue query loads first (in flight during the pack) ----
    int n0 = base + lr;       if (n0 >= N) n0 = N - 1;
    int n1 = base + 16 + lr;  if (n1 >= N) n1 = N - 1;
    const float4* r0 = (const float4*)(qb + (size_t)n0 * FIN);
    const float4* r1 = (const float4*)(qb + (size_t)n1 * FIN);
    float4 a0[8], a1[8];
    #pragma unroll
    for (int kk = 0; kk < 4; ++kk) {
        a0[2 * kk]     = r0[kk * 8 + lg * 2];
        a0[2 * kk + 1] = r0[kk * 8 + lg * 2 + 1];
        a1[2 * kk]     = r1[kk * 8 + lg * 2];
        a1[2 * kk + 1] = r1[kk * 8 + lg * 2 + 1];
    }

    // ---- pack W1 -> LDS (overlaps pending query loads) ----
    #pragma unroll
    for (int it = 0; it < 4; ++it) {
        int p = it * 256 + tid;        // fragment-row 0..1023
        int g6 = p >> 6;               // kk*4+nt
        int kk = g6 >> 2, nt = g6 & 3;
        int lane6 = p & 63;
        int plg = lane6 >> 4, plr = lane6 & 15;
        int f = nt * 16 + plr;
        int kbase = kk * 32 + plg * 8;
        f16x8 fr;
        #pragma unroll
        for (int j = 0; j < 8; ++j)
            fr[j] = (_Float16)W1[(kbase + j) * FOUT + f];
        ((f16x8*)Wlds)[p] = fr;
    }
    __syncthreads();
    const f16x8* Bp = (const f16x8*)Wlds;

    f32x4 acc0[4], acc1[4];
    #pragma unroll
    for (int nt = 0; nt < 4; ++nt) { acc0[nt] = (f32x4)0.f; acc1[nt] = (f32x4)0.f; }

    #pragma unroll
    for (int kk = 0; kk < 4; ++kk) {
        f16x8 A0, A1;
        const float* x0 = (const float*)&a0[2 * kk];
        const float* x1 = (const float*)&a1[2 * kk];
        #pragma unroll
        for (int j = 0; j < 8; ++j) { A0[j] = (_Float16)x0[j]; A1[j] = (_Float16)x1[j]; }
        #pragma unroll
        for (int nt = 0; nt < 4; ++nt) {
            f16x8 Bf = Bp[(kk * 4 + nt) * 64 + lane];
            acc0[nt] = __builtin_amdgcn_mfma_f32_16x16x32_f16(A0, Bf, acc0[nt], 0, 0, 0);
            acc1[nt] = __builtin_amdgcn_mfma_f32_16x16x32_f16(A1, Bf, acc1[nt], 0, 0, 0);
        }
    }
    #pragma unroll
    for (int r = 0; r < 4; ++r) {
        int m0 = base + lg * 4 + r;
        int m1 = base + 16 + lg * 4 + r;
        if (m0 < N) {
            #pragma unroll
            for (int nt = 0; nt < 4; ++nt)
                yq[(size_t)m0 * FOUT + nt * 16 + lr] = __float2half(acc0[nt][r]);
        }
        if (m1 < N) {
            #pragma unroll
            for (int nt = 0; nt < 4; ++nt)
                yq[(size_t)m1 * FOUT + nt * 16 + lr] = __float2half(acc1[nt][r]);
        }
    }
}

// ---------------- Stage 2: s1 = tanh(mean_k y[e]+b1).W2 ----------------
// 4 node-chains per wave-half: 32 independent gathers in flight.
__global__ __launch_bounds__(256, 4) void k_agg(const __half* __restrict__ y,
                                                const int* __restrict__ edges,
                                                const float* __restrict__ b1,
                                                const float* __restrict__ W2,
                                                float* __restrict__ s1, int N) {
    const int tid = threadIdx.x;
    const int wave = tid >> 6, lane = tid & 63;
    const int half = lane >> 5, fl = lane & 31;
    const int q = blockIdx.y;
    const int base = blockIdx.x * 32 + wave * 8 + half;   // chains at base+2c
    const __half2* y2 = (const __half2*)(y + (size_t)q * N * FOUT);

    int n[4], nc[4];
    #pragma unroll
    for (int c = 0; c < 4; ++c) {
        n[c] = base + 2 * c;
        nc[c] = n[c] < N ? n[c] : N - 1;
    }
    int4 ea[4], eb[4];
    #pragma unroll
    for (int c = 0; c < 4; ++c) {
        const int4* er = (const int4*)(edges + (size_t)nc[c] * KN);
        ea[c] = er[0];
        eb[c] = er[1];
    }
    __half2 v[4][8];
    #pragma unroll
    for (int c = 0; c < 4; ++c) {
        v[c][0] = y2[(size_t)ea[c].x * 32 + fl];
        v[c][1] = y2[(size_t)ea[c].y * 32 + fl];
        v[c][2] = y2[(size_t)ea[c].z * 32 + fl];
        v[c][3] = y2[(size_t)ea[c].w * 32 + fl];
        v[c][4] = y2[(size_t)eb[c].x * 32 + fl];
        v[c][5] = y2[(size_t)eb[c].y * 32 + fl];
        v[c][6] = y2[(size_t)eb[c].z * 32 + fl];
        v[c][7] = y2[(size_t)eb[c].w * 32 + fl];
    }

    float2 bv = *(const float2*)(b1 + fl * 2);
    float2 wv = *(const float2*)(W2 + fl * 2);

    float p[4];
    #pragma unroll
    for (int c = 0; c < 4; ++c) {
        __half2 s01 = __hadd2(v[c][0], v[c][1]), s23 = __hadd2(v[c][2], v[c][3]);
        __half2 s45 = __hadd2(v[c][4], v[c][5]), s67 = __hadd2(v[c][6], v[c][7]);
        __half2 sum = __hadd2(__hadd2(s01, s23), __hadd2(s45, s67));
        float2 sf = __half22float2(sum);
        float x0 = sf.x * 0.125f + bv.x;
        float x1 = sf.y * 0.125f + bv.y;
        float e0 = __expf(-2.f * fabsf(x0)), e1 = __expf(-2.f * fabsf(x1));
        float t0 = copysignf(__fdividef(1.f - e0, 1.f + e0), x0);
        float t1 = copysignf(__fdividef(1.f - e1, 1.f + e1), x1);
        p[c] = t0 * wv.x + t1 * wv.y;
    }
    #pragma unroll
    for (int off = 16; off; off >>= 1) {
        p[0] += __shfl_xor(p[0], off);
        p[1] += __shfl_xor(p[1], off);
        p[2] += __shfl_xor(p[2], off);
        p[3] += __shfl_xor(p[3], off);
    }
    if (fl == 0) {
        float* s1q = s1 + (size_t)q * N;
        #pragma unroll
        for (int c = 0; c < 4; ++c)
            if (n[c] < N) s1q[n[c]] = p[c];
    }
}

// ---------------- Stage 3 (fused): score + exp + Z-partial + weighted values ----------------
__global__ __launch_bounds__(256, 4) void k_ctx(const float* __restrict__ values,
                                                const float* __restrict__ s1,
                                                const int* __restrict__ edges,
                                                const float* __restrict__ b2,
                                                float* __restrict__ score,
                                                float* __restrict__ partial,
                                                float* __restrict__ zpart, int N) {
    const int q = blockIdx.y, cb = blockIdx.x;
    const int tid = threadIdx.x;
    const int n0 = cb * CHUNK, n1 = min(n0 + CHUNK, N);
    const int cnt = n1 - n0;
    __shared__ float wlds[256];
    __shared__ float zred[4];
    const float* s1q = s1 + (size_t)q * N;
    const float b2v = b2[0];

    float zp = 0.f;
    if (tid < cnt) {
        int n = n0 + tid;
        float acc = 0.f;
        #pragma unroll
        for (int k = 0; k < KN; ++k) acc += s1q[edges[(size_t)n * KN + k]];
        float sc = acc * 0.125f + b2v;
        score[(size_t)q * N + n] = sc;
        float ex = __expf(sc);
        wlds[tid] = ex;
        zp = ex;
    }
    float z = zp;
    #pragma unroll
    for (int off = 32; off; off >>= 1) z += __shfl_xor(z, off);
    if ((tid & 63) == 0) zred[tid >> 6] = z;
    __syncthreads();

    const int fi = tid & 31, g = tid >> 5;
    const float4* v = (const float4*)(values + (size_t)q * N * FIN);
    float4 acc = make_float4(0.f, 0.f, 0.f, 0.f);
    int n = n0 + g;
    for (; n + 56 < n1; n += 64) {
        int l = n - n0;
        float w0 = wlds[l],      w1 = wlds[l + 8],  w2 = wlds[l + 16], w3 = wlds[l + 24];
        float w4 = wlds[l + 32], w5 = wlds[l + 40], w6 = wlds[l + 48], w7 = wlds[l + 56];
        float4 v0 = v[(size_t)n * 32 + fi];
        float4 v1 = v[(size_t)(n + 8) * 32 + fi];
        float4 v2 = v[(size_t)(n + 16) * 32 + fi];
        float4 v3 = v[(size_t)(n + 24) * 32 + fi];
        float4 v4 = v[(size_t)(n + 32) * 32 + fi];
        float4 v5 = v[(size_t)(n + 40) * 32 + fi];
        float4 v6 = v[(size_t)(n + 48) * 32 + fi];
        float4 v7 = v[(size_t)(n + 56) * 32 + fi];
        acc.x = fmaf(w0, v0.x, acc.x); acc.y = fmaf(w0, v0.y, acc.y);
        acc.z = fmaf(w0, v0.z, acc.z); acc.w = fmaf(w0, v0.w, acc.w);
        acc.x = fmaf(w1, v1.x, acc.x); acc.y = fmaf(w1, v1.y, acc.y);
        acc.z = fmaf(w1, v1.z, acc.z); acc.w = fmaf(w1, v1.w, acc.w);
        acc.x = fmaf(w2, v2.x, acc.x); acc.y = fmaf(w2, v2.y, acc.y);
        acc.z = fmaf(w2, v2.z, acc.z); acc.w = fmaf(w2, v2.w, acc.w);
        acc.x = fmaf(w3, v3.x, acc.x); acc.y = fmaf(w3, v3.y, acc.y);
        acc.z = fmaf(w3, v3.z, acc.z); acc.w = fmaf(w3, v3.w, acc.w);
        acc.x = fmaf(w4, v4.x, acc.x); acc.y = fmaf(w4, v4.y, acc.y);
        acc.z = fmaf(w4, v4.z, acc.z); acc.w = fmaf(w4, v4.w, acc.w);
        acc.x = fmaf(w5, v5.x, acc.x); acc.y = fmaf(w5, v5.y, acc.y);
        acc.z = fmaf(w5, v5.z, acc.z); acc.w = fmaf(w5, v5.w, acc.w);
        acc.x = fmaf(w6, v6.x, acc.x); acc.y = fmaf(w6, v6.y, acc.y);
        acc.z = fmaf(w6, v6.z, acc.z); acc.w = fmaf(w6, v6.w, acc.w);
        acc.x = fmaf(w7, v7.x, acc.x); acc.y = fmaf(w7, v7.y, acc.y);
        acc.z = fmaf(w7, v7.z, acc.z); acc.w = fmaf(w7, v7.w, acc.w);
    }
    for (; n < n1; n += 8) {
        float ww = wlds[n - n0];
        float4 a = v[(size_t)n * 32 + fi];
        acc.x = fmaf(ww, a.x, acc.x);
        acc.y = fmaf(ww, a.y, acc.y);
        acc.z = fmaf(ww, a.z, acc.z);
        acc.w = fmaf(ww, a.w, acc.w);
    }
    __shared__ float4 part[256];
    part[tid] = acc;
    __syncthreads();
    if (tid < 32) {
        float4 a = part[tid];
        #pragma unroll
        for (int gg = 1; gg < 8; ++gg) {
            float4 b = part[gg * 32 + tid];
            a.x += b.x; a.y += b.y; a.z += b.z; a.w += b.w;
        }
        ((float4*)partial)[((size_t)q * CTXB + cb) * 32 + fi] = a;
    }
    if (tid == 0) zpart[(size_t)q * CTXB + cb] = zred[0] + zred[1] + zred[2] + zred[3];
}

// ---------------- Stage 4: ctx[q,f] = (Σ_cb partial[q,cb,f]) / (Σ_cb zpart[q,cb]) ----------------
__global__ __launch_bounds__(512) void k_final(const float* __restrict__ partial,
                                               const float* __restrict__ zpart,
                                               float* __restrict__ ctx) {
    const int q = blockIdx.x;
    const int tid = threadIdx.x;
    const int f = tid & 127, h = tid >> 7;
    const float* p = partial + (size_t)q * CTXB * FIN;
    float s = 0.f;
    for (int b = h; b < CTXB; b += 4) s += p[(size_t)b * FIN + f];
    __shared__ float red[512];
    __shared__ float zred[8];
    red[tid] = s;
    float z = (tid < CTXB) ? zpart[(size_t)q * CTXB + tid] : 0.f;
    #pragma unroll
    for (int off = 32; off; off >>= 1) z += __shfl_xor(z, off);
    if ((tid & 63) == 0) zred[tid >> 6] = z;
    __syncthreads();
    if (tid < 128) {
        float Zt = zred[0] + zred[1] + zred[2] + zred[3] +
                   zred[4] + zred[5] + zred[6] + zred[7];
        float t = red[tid] + red[tid + 128] + red[tid + 256] + red[tid + 384];
        ctx[q * FIN + f] = t * (1.f / Zt);
    }
}

extern "C" void kernel_launch(void* const* d_in, const int* in_sizes, int n_in,
                              void* d_out, int out_size, void* d_ws, size_t ws_size,
                              hipStream_t stream) {
    const float* query  = (const float*)d_in[0];
    const float* values = (const float*)d_in[1];
    const int*   edges  = (const int*)d_in[2];
    const float* W1     = (const float*)d_in[3];
    const float* b1     = (const float*)d_in[4];
    const float* W2     = (const float*)d_in[5];
    const float* b2     = (const float*)d_in[6];

    int N = in_sizes[2] / KN;                 // 50000
    int Q = in_sizes[0] / (N * FIN);          // 4

    float* out   = (float*)d_out;
    float* ctx   = out;                       // [Q,128]
    float* score = out + (size_t)Q * FIN;     // [Q,N]

    char* ws = (char*)d_ws;
    __half* y = (__half*)ws;                                    // [Q,N,64] f16
    size_t off = (size_t)Q * N * FOUT * sizeof(__half);
    float* s1    = (float*)(ws + off);  off += (size_t)Q * N * sizeof(float);
    float* part  = (float*)(ws + off);  off += (size_t)Q * CTXB * FIN * sizeof(float);
    float* zpart = (float*)(ws + off);                          // [Q,CTXB]

    dim3 g1((N + 127) / 128, Q);
    k_xw<<<g1, 256, 0, stream>>>(query, W1, y, N);
    dim3 g2((N + 31) / 32, Q);
    k_agg<<<g2, 256, 0, stream>>>(y, edges, b1, W2, s1, N);
    dim3 g3(CTXB, Q);
    k_ctx<<<g3, 256, 0, stream>>>(values, s1, edges, b2, score, part, zpart, N);
    k_final<<<Q, 512, 0, stream>>>(part, zpart, ctx);
}